// Round 10
// baseline (214.492 us; speedup 1.0000x reference)
//
#include <hip/hip_runtime.h>
#include <math.h>

typedef _Float16 f16;
typedef _Float16 half8 __attribute__((ext_vector_type(8)));
typedef float f32x16 __attribute__((ext_vector_type(16)));

#define DEV __device__ __forceinline__

// ---------------- workspace layout (bytes) ----------------
#define W1F_OFF 0        // [L][nt2]      : 16 frags  = 16 KB
#define W2F_OFF 16384    // [L][kt4][nt2] : 64 frags  = 64 KB
#define WOF_OFF 81920    // [L][u8][kt4]  : 256 frags = 256 KB (used cols, 32-padded)
#define BOF_OFF 344064   // [L][u8][32] fp32 bias for used cols = 8 KB
#define SUMLOG_OFF 352256 // 1 fp32: sum over all layers/features of log|scale|

// ---------------- LDS layout ----------------
// Per-wave private 6400 B chunk at lds + wv*6400. Regions alias in time
// (all DS ops are same-wave, in-order; compiler can't reorder across the
// aliasing char* accesses):
//   H phase: 32 samples x 144 B (h1 then h2, f16, 128+16 pad)      = 4608 B
//   P phase: 2 slots x 32 samples x 100 B (25 fp32 spline params)  = 6400 B
#define WCHUNK    6400
#define H_STRIDE  144
#define P_SLOT    3200
#define P_STRIDE  100
#define LDS_BYTES 25600   // 4 waves * 6400

DEV float frcp(float x){ return __builtin_amdgcn_rcpf(x); }
DEV float fexp(float x){ return __expf(x); }
DEV float flog(float x){ return __logf(x); }

// tanh = 1 - 2/(e^{2x}+1). Robust without clamp (saturates correctly at +-inf).
DEV float ftanh(float x){
  float e = fexp(2.f * x);
  float r = frcp(e + 1.f);
  return fmaf(-2.f, r, 1.f);
}

// Rational-quadratic spline forward + log-det, reading params from LDS in
// three register-lean phases: widths (p[0..7]) -> running-cumsum x-path,
// heights (p[8..15]) -> masked partial-sum y-path, derivs (p[16..24]) ->
// 2-point select + softplus.
DEV void rq_spline_lds(const char* pb, float xv, float &y_out, float &ld_out)
{
  // ---- phase 1: widths ----
  float ew[8]; float sw = 0.f;
#pragma unroll
  for (int k = 0; k < 8; ++k){
    float pw = *(const float*)(pb + k * 4);
    ew[k] = fexp(pw); sw += ew[k];
  }
  float rw = frcp(sw) * 19.9992f;           // (RMAX-RMIN) - K*MIN_BIN

  int idx = 0;
  float xk = -10.f, ewk = ew[0];
  float cum = fmaf(ew[0], rw, -10.f + 1e-4f);   // xpos[1]
#pragma unroll
  for (int j = 1; j < 8; ++j){
    bool sel = (xv >= cum);
    idx += sel ? 1 : 0;
    xk  = sel ? cum   : xk;
    ewk = sel ? ew[j] : ewk;
    cum = fmaf(ew[j], rw, cum + 1e-4f);         // xpos[j+1]
  }
  float bw = fmaf(ewk, rw, 1e-4f);

  // ---- phase 2: heights ----
  float eh[8]; float shs = 0.f;
#pragma unroll
  for (int k = 0; k < 8; ++k){
    float ph = *(const float*)(pb + 32 + k * 4);
    eh[k] = fexp(ph); shs += eh[k];
  }
  float rh = frcp(shs) * 19.9992f;

  float S = 0.f, ehk = eh[0];
#pragma unroll
  for (int k = 1; k < 8; ++k){
    bool sel = (idx >= k);
    S   += sel ? eh[k - 1] : 0.f;
    ehk  = sel ? eh[k]     : ehk;
  }
  float yk = fmaf(S, rh, fmaf((float)idx, 1e-4f, -10.f));
  float bh = fmaf(ehk, rh, 1e-4f);

  // ---- phase 3: derivatives (select 2 of 9, then softplus) ----
  float uA = *(const float*)(pb + 64);
  float uB = *(const float*)(pb + 68);
#pragma unroll
  for (int j = 1; j < 8; ++j){
    bool sel = (idx >= j);
    float pa = *(const float*)(pb + 64 + j * 4);
    float pc = *(const float*)(pb + 68 + j * 4);
    uA = sel ? pa : uA;
    uB = sel ? pc : uB;
  }
  float vA = uA + 0.54116666f;
  float dk  = fmaxf(vA, 0.f) + flog(1.f + fexp(-fabsf(vA))) + 1e-4f;
  float vB = uB + 0.54116666f;
  float dk1 = fmaxf(vB, 0.f) + flog(1.f + fexp(-fabsf(vB))) + 1e-4f;

  float rbw = frcp(bw);
  float s   = bh * rbw;
  float zf  = fminf(fmaxf((xv - xk) * rbw, 0.f), 1.f);
  float z1  = 1.f - zf;
  float zz  = zf * zf, z01 = zf * z1;
  float den = s + (dk1 + dk - 2.f * s) * z01;
  float rden = frcp(den);
  float yv  = yk + bh * (s * zz + dk * z01) * rden;
  float num = dk1 * zz + 2.f * s * z01 + dk * z1 * z1;
  float ldv = flog(s * s * num * rden * rden);

  bool outside = (xv <= -10.f) || (xv >= 10.f);
  y_out  = outside ? xv : yv;
  ld_out = outside ? 0.f : ldv;
}

// ---------------- prep kernel: pack fp16 B-fragments into ws ----------------
extern "C" __global__ void __launch_bounds__(256)
prep_kernel(const float* __restrict__ W1, const float* __restrict__ W2,
            const float* __restrict__ Wo, const float* __restrict__ bout,
            const float* __restrict__ scale, char* __restrict__ ws)
{
  int tid = blockIdx.x * 256 + threadIdx.x;
  if (tid < 1024){                       // W1 frags: [L][nt2]
    int fi = tid >> 6, lane = tid & 63;
    int l = fi >> 1, nt = fi & 1;
    int n = nt * 32 + (lane & 31), khi = lane >> 5;
    half8 h;
#pragma unroll
    for (int j = 0; j < 8; ++j){ int k = khi * 8 + j; h[j] = (f16)W1[l * 1024 + k * 64 + n]; }
    *(half8*)(ws + W1F_OFF + fi * 1024 + lane * 16) = h;
  } else if (tid < 5120){                // W2 frags: [L][kt4][nt2]
    int idx = tid - 1024;
    int fi = idx >> 6, lane = idx & 63;
    int l = fi >> 3, kt = (fi >> 1) & 3, nt = fi & 1;
    int n = nt * 32 + (lane & 31), khi = lane >> 5;
    half8 h;
#pragma unroll
    for (int j = 0; j < 8; ++j){ int k = kt * 16 + khi * 8 + j; h[j] = (f16)W2[l * 4096 + k * 64 + n]; }
    *(half8*)(ws + W2F_OFF + fi * 1024 + lane * 16) = h;
  } else if (tid < 21504){               // Wout used-col frags: [L][u8][kt4]
    int idx = tid - 5120;
    int fi = idx >> 6, lane = idx & 63;
    int l = fi >> 5, u = (fi >> 2) & 7, kt = fi & 3;
    int f = (l & 1) + 2 * u;
    int c = lane & 31, khi = lane >> 5;
    half8 h;
#pragma unroll
    for (int j = 0; j < 8; ++j){
      int k = kt * 16 + khi * 8 + j;
      float v = (c < 25) ? Wo[l * 25600 + k * 400 + f * 25 + c] : 0.f;
      h[j] = (f16)v;
    }
    *(half8*)(ws + WOF_OFF + fi * 1024 + lane * 16) = h;
  } else if (tid < 23552){               // bout used cols: [L][u8][32] fp32
    int idx = tid - 21504;
    int l = idx >> 8, u = (idx >> 5) & 7, c = idx & 31;
    int f = (l & 1) + 2 * u;
    float v = (c < 25) ? bout[l * 400 + f * 25 + c] : 0.f;
    ((float*)(ws + BOF_OFF))[idx] = v;
  } else if (tid == 23552){              // sum of log|scale| over all layers
    float acc = 0.f;
    for (int i = 0; i < 128; ++i) acc += logf(fabsf(scale[i]));
    *(float*)(ws + SUMLOG_OFF) = acc;
  }
}

// ---------------- one coupling layer ----------------
// Wave owns 32 samples; lane pair (ln31, khi=0/1) shares sample ln31.
// khi=0 splines features PAR+2it (it=0..3), khi=1 splines PAR+2it+8 —
// same instruction stream, no divergence. z exchanged via shfl_xor(32).
template<int PAR>
DEV void layer_mfma(int l,
                    const float* __restrict__ W0, const float* __restrict__ b0,
                    const float* __restrict__ b1v, const float* __restrict__ b2v,
                    const float* __restrict__ scv, const float* __restrict__ shv,
                    const char* __restrict__ ws, char* wlds /*per-wave chunk*/,
                    float (&z)[16], float &logdet,
                    int lane, int ln31, int khi)
{
  const float* w0  = W0 + l * 256;
  const float* bb0 = b0 + l * 16;
  const int rowbase = khi * 4;     // C/D layout: row = (i&3)+8*(i>>2)+4*khi

  const half8* W1F = (const half8*)(ws + W1F_OFF);
  const half8* W2F = (const half8*)(ws + W2F_OFF);
  const half8* WOF = (const half8*)(ws + WOF_OFF);
  const float* BOF = (const float*)(ws + BOF_OFF);

  // ---- hoisted W1 fragment + bias loads (latency hidden behind h0) ----
  half8 w1f[2];
#pragma unroll
  for (int nt = 0; nt < 2; ++nt) w1f[nt] = W1F[(l * 2 + nt) * 64 + lane];
  float bias1[2], bias2[2];
#pragma unroll
  for (int nt = 0; nt < 2; ++nt){
    bias1[nt] = b1v[l * 64 + nt * 32 + ln31];
    bias2[nt] = b2v[l * 64 + nt * 32 + ln31];
  }

  // ---- h0 = tanh(mz @ W0 + b0): scalar weights; keep own khi-half as
  //      the W1 A-fragment. No LDS round-trip. ----
  float h0[16];
#pragma unroll
  for (int j = 0; j < 16; ++j) h0[j] = bb0[j];
#pragma unroll
  for (int u = 0; u < 8; ++u){
    const int f = (1 - PAR) + 2 * u;
    const float v = z[f];
#pragma unroll
    for (int j = 0; j < 16; ++j) h0[j] = fmaf(v, w0[f * 16 + j], h0[j]);
  }
  half8 a0;
#pragma unroll
  for (int j = 0; j < 8; ++j){
    float hv = khi ? h0[j + 8] : h0[j];
    a0[j] = (f16)ftanh(hv);
  }

  // ---- W1: h1 = tanh(h0 @ W1 + b1), 1 m-tile ----
  f32x16 d1[2];
#pragma unroll
  for (int nt = 0; nt < 2; ++nt)
#pragma unroll
    for (int i = 0; i < 16; ++i) d1[nt][i] = bias1[nt];
#pragma unroll
  for (int nt = 0; nt < 2; ++nt)
    d1[nt] = __builtin_amdgcn_mfma_f32_32x32x16_f16(a0, w1f[nt], d1[nt], 0, 0, 0);

  // load W2 frags now; the d1 epilogue below covers the latency
  half8 w2f[8];
#pragma unroll
  for (int kt = 0; kt < 4; ++kt)
#pragma unroll
    for (int nt = 0; nt < 2; ++nt)
      w2f[kt * 2 + nt] = W2F[((l * 4 + kt) * 2 + nt) * 64 + lane];

#pragma unroll
  for (int nt = 0; nt < 2; ++nt)
#pragma unroll
    for (int i = 0; i < 16; ++i){
      int row = (i & 3) + 8 * (i >> 2) + rowbase;
      *(f16*)(wlds + row * H_STRIDE + (nt * 32 + ln31) * 2) = (f16)ftanh(d1[nt][i]);
    }

  // ---- W2: h2 = h1 @ W2 + b2 ----
  half8 a1[4];
#pragma unroll
  for (int kt = 0; kt < 4; ++kt)
    a1[kt] = *(const half8*)(wlds + ln31 * H_STRIDE + kt * 32 + khi * 16);
  f32x16 d2[2];
#pragma unroll
  for (int nt = 0; nt < 2; ++nt)
#pragma unroll
    for (int i = 0; i < 16; ++i) d2[nt][i] = bias2[nt];
#pragma unroll
  for (int kt = 0; kt < 4; ++kt)
#pragma unroll
    for (int nt = 0; nt < 2; ++nt)
      d2[nt] = __builtin_amdgcn_mfma_f32_32x32x16_f16(a1[kt], w2f[kt * 2 + nt], d2[nt], 0, 0, 0);

  // prefetch production 0's A-side Wout frags during the d2 epilogue
  half8 bfA[4];
#pragma unroll
  for (int kt = 0; kt < 4; ++kt) bfA[kt] = WOF[((l * 8 + 0) * 4 + kt) * 64 + lane];
  float biasA = BOF[(l * 8 + 0) * 32 + ln31];

#pragma unroll
  for (int nt = 0; nt < 2; ++nt)
#pragma unroll
    for (int i = 0; i < 16; ++i){
      int row = (i & 3) + 8 * (i >> 2) + rowbase;
      *(f16*)(wlds + row * H_STRIDE + (nt * 32 + ln31) * 2) = (f16)d2[nt][i];
    }

  // ---- h2 A-fragments (live across all 4 production iterations) ----
  half8 a2[4];
#pragma unroll
  for (int kt = 0; kt < 4; ++kt)
    a2[kt] = *(const half8*)(wlds + ln31 * H_STRIDE + kt * 32 + khi * 16);

  // ---- paired productions + splines (sequential dp to cap registers) ----
#pragma unroll 1
  for (int it = 0; it < 4; ++it){
    // B-side frags: issue loads, then cover latency with dpA's MFMA+store
    half8 bfB[4];
#pragma unroll
    for (int kt = 0; kt < 4; ++kt) bfB[kt] = WOF[((l * 8 + it + 4) * 4 + kt) * 64 + lane];
    float biasB = BOF[(l * 8 + it + 4) * 32 + ln31];

    {
      f32x16 dp;
#pragma unroll
      for (int i = 0; i < 16; ++i) dp[i] = biasA;
#pragma unroll
      for (int kt = 0; kt < 4; ++kt)
        dp = __builtin_amdgcn_mfma_f32_32x32x16_f16(a2[kt], bfA[kt], dp, 0, 0, 0);
      if (ln31 < 25){
#pragma unroll
        for (int i = 0; i < 16; ++i){
          int row = (i & 3) + 8 * (i >> 2) + rowbase;
          *(float*)(wlds + row * P_STRIDE + ln31 * 4) = dp[i];
        }
      }
    }
    {
      f32x16 dp;
#pragma unroll
      for (int i = 0; i < 16; ++i) dp[i] = biasB;
#pragma unroll
      for (int kt = 0; kt < 4; ++kt)
        dp = __builtin_amdgcn_mfma_f32_32x32x16_f16(a2[kt], bfB[kt], dp, 0, 0, 0);
      if (ln31 < 25){
#pragma unroll
        for (int i = 0; i < 16; ++i){
          int row = (i & 3) + 8 * (i >> 2) + rowbase;
          *(float*)(wlds + P_SLOT + row * P_STRIDE + ln31 * 4) = dp[i];
        }
      }
    }

    // prefetch next iteration's A-side frags; spline below hides the latency
    if (it < 3){
#pragma unroll
      for (int kt = 0; kt < 4; ++kt) bfA[kt] = WOF[((l * 8 + it + 1) * 4 + kt) * 64 + lane];
      biasA = BOF[(l * 8 + it + 1) * 32 + ln31];
    }

    // own-sample spline, params streamed from own khi-slot
    // (in-order per-wave DS + compiler aliasing on lds => reads stay after stores)
    const char* pb = wlds + khi * P_SLOT + ln31 * P_STRIDE;
    float xlo = z[PAR + 2 * it], xhi = z[PAR + 2 * it + 8];
    float xin = khi ? xhi : xlo;
    float y, ld;
    rq_spline_lds(pb, xin, y, ld);
    logdet += ld;
    z[PAR + 2 * it]     = khi ? xlo : y;
    z[PAR + 2 * it + 8] = khi ? y : xhi;
  }

  // ---- exchange transformed features between the khi-halves ----
#pragma unroll
  for (int it = 0; it < 4; ++it){
    float mine  = khi ? z[PAR + 2 * it + 8] : z[PAR + 2 * it];
    float other = __shfl_xor(mine, 32, 64);
    z[PAR + 2 * it]     = khi ? other : z[PAR + 2 * it];
    z[PAR + 2 * it + 8] = khi ? z[PAR + 2 * it + 8] : other;
  }

  // ---- affine (log|scale| sum precomputed in prep) ----
  const float* scp = scv + l * 16;
  const float* shp = shv + l * 16;
#pragma unroll
  for (int j = 0; j < 16; ++j)
    z[j] = fmaf(z[j], scp[j], shp[j]);
}

extern "C" __global__ void __launch_bounds__(256, 3)
flow_kernel(const float* __restrict__ x,
            const float* __restrict__ W0, const float* __restrict__ b0,
            const float* __restrict__ b1v, const float* __restrict__ b2v,
            const float* __restrict__ scv, const float* __restrict__ shv,
            const char* __restrict__ ws, float* __restrict__ out, int B)
{
  extern __shared__ char lds[];
  const int t    = threadIdx.x;
  const int lane = t & 63;
  const int wv   = t >> 6;
  const int ln31 = lane & 31;
  const int khi  = lane >> 5;
  char* wlds = lds + wv * WCHUNK;          // per-wave private chunk

  const int sid = wv * 32 + ln31;          // sample within block (0..127)
  const int g   = blockIdx.x * 128 + sid;  // global sample

  float z[16];
  const float4* xv = reinterpret_cast<const float4*>(x + (size_t)g * 16);
  float4 a0 = xv[0], a1 = xv[1], a2 = xv[2], a3 = xv[3];
  z[0]=a0.x; z[1]=a0.y; z[2]=a0.z; z[3]=a0.w;
  z[4]=a1.x; z[5]=a1.y; z[6]=a1.z; z[7]=a1.w;
  z[8]=a2.x; z[9]=a2.y; z[10]=a2.z; z[11]=a2.w;
  z[12]=a3.x; z[13]=a3.y; z[14]=a3.z; z[15]=a3.w;

  float logdet = 0.f;
  for (int l = 7; l >= 0; --l){
    if (l & 1) layer_mfma<1>(l, W0, b0, b1v, b2v, scv, shv, ws, wlds, z, logdet, lane, ln31, khi);
    else       layer_mfma<0>(l, W0, b0, b1v, b2v, scv, shv, ws, wlds, z, logdet, lane, ln31, khi);
  }

  // combine the pair's logdet halves
  float ldtot = logdet + __shfl_xor(logdet, 32, 64);

  float sumlog = *(const float*)(ws + SUMLOG_OFF);
  float ss = 0.f;
#pragma unroll
  for (int j = 0; j < 16; ++j) ss = fmaf(z[j], z[j], ss);
  if (khi == 0)
    out[g] = -0.5f * ss - 14.7030165f + ldtot + sumlog;
}

extern "C" void kernel_launch(void* const* d_in, const int* in_sizes, int n_in,
                              void* d_out, int out_size, void* d_ws, size_t ws_size,
                              hipStream_t stream)
{
  const float* x    = (const float*)d_in[0];
  const float* W0   = (const float*)d_in[1];
  const float* b0   = (const float*)d_in[2];
  const float* W1   = (const float*)d_in[3];
  const float* b1   = (const float*)d_in[4];
  const float* W2   = (const float*)d_in[5];
  const float* b2   = (const float*)d_in[6];
  const float* Wout = (const float*)d_in[7];
  const float* bout = (const float*)d_in[8];
  const float* scale= (const float*)d_in[9];
  const float* shift= (const float*)d_in[10];

  int B = in_sizes[0] / 16;

  hipLaunchKernelGGL(prep_kernel, dim3(93), dim3(256), 0, stream,
                     W1, W2, Wout, bout, scale, (char*)d_ws);

  hipLaunchKernelGGL(flow_kernel, dim3(B / 128), dim3(256), LDS_BYTES, stream,
                     x, W0, b0, b1, b2, scale, shift,
                     (const char*)d_ws, (float*)d_out, B);
}

// Round 11
// 213.907 us; speedup vs baseline: 1.0027x; 1.0027x over previous
//
#include <hip/hip_runtime.h>
#include <math.h>

typedef _Float16 f16;
typedef _Float16 half8 __attribute__((ext_vector_type(8)));
typedef float f32x16 __attribute__((ext_vector_type(16)));
typedef float f32x2  __attribute__((ext_vector_type(2)));

#define DEV __device__ __forceinline__

// ---------------- workspace layout (bytes) ----------------
#define W1F_OFF 0        // [L][nt2]      : 16 frags  = 16 KB
#define W2F_OFF 16384    // [L][kt4][nt2] : 64 frags  = 64 KB
#define WOF_OFF 81920    // [L][u8][kt4]  : 256 frags = 256 KB (used cols, 32-padded)
#define BOF_OFF 344064   // [L][u8][32] fp32 bias for used cols = 8 KB
#define SUMLOG_OFF 352256 // 1 fp32: sum over all layers/features of log|scale|

// ---------------- LDS layout ----------------
// Per-wave private 7680 B chunk at lds + wv*7680. Regions alias in time
// (all DS ops are same-wave, in-order; compiler can't reorder across the
// aliasing char* accesses):
//   H phase: 32 samples x 144 B (h1 then h2, f16, 128+16 pad)      = 4608 B
//   P phase: 2 slots x 32 samples x 120 B (25 fp32, 8B-aligned)    = 7680 B
//   (P lane stride 120 B = 30 banks -> only 2-way aliasing: free)
#define WCHUNK    7680
#define H_STRIDE  144
#define P_SLOT    3840
#define P_STRIDE  120
#define LDS_BYTES 30720   // 4 waves * 7680

DEV float frcp(float x){ return __builtin_amdgcn_rcpf(x); }
DEV float fexp(float x){ return __expf(x); }
DEV float flog(float x){ return __logf(x); }

// tanh = 1 - 2/(e^{2x}+1). Robust without clamp (saturates correctly at +-inf).
DEV float ftanh(float x){
  float e = fexp(2.f * x);
  float r = frcp(e + 1.f);
  return fmaf(-2.f, r, 1.f);
}

// Rational-quadratic spline forward + log-det, reading params from LDS in
// three phases with b64 vector loads: widths (p[0..7]) -> running-cumsum
// x-path, heights (p[8..15]) -> masked partial-sum y-path, derivs
// (p[16..24]) -> 2-point select + softplus.
DEV void rq_spline_lds(const char* pb, float xv, float &y_out, float &ld_out)
{
  // ---- phase 1: widths (4 x ds_read_b64) ----
  float ew[8]; float sw = 0.f;
#pragma unroll
  for (int k2 = 0; k2 < 4; ++k2){
    f32x2 v = *(const f32x2*)(pb + k2 * 8);
    ew[2*k2]   = fexp(v.x);
    ew[2*k2+1] = fexp(v.y);
    sw += ew[2*k2] + ew[2*k2+1];
  }
  float rw = frcp(sw) * 19.9992f;           // (RMAX-RMIN) - K*MIN_BIN

  int idx = 0;
  float xk = -10.f, ewk = ew[0];
  float cum = fmaf(ew[0], rw, -10.f + 1e-4f);   // xpos[1]
#pragma unroll
  for (int j = 1; j < 8; ++j){
    bool sel = (xv >= cum);
    idx += sel ? 1 : 0;
    xk  = sel ? cum   : xk;
    ewk = sel ? ew[j] : ewk;
    cum = fmaf(ew[j], rw, cum + 1e-4f);         // xpos[j+1]
  }
  float bw = fmaf(ewk, rw, 1e-4f);

  // ---- phase 2: heights (4 x ds_read_b64) ----
  float eh[8]; float shs = 0.f;
#pragma unroll
  for (int k2 = 0; k2 < 4; ++k2){
    f32x2 v = *(const f32x2*)(pb + 32 + k2 * 8);
    eh[2*k2]   = fexp(v.x);
    eh[2*k2+1] = fexp(v.y);
    shs += eh[2*k2] + eh[2*k2+1];
  }
  float rh = frcp(shs) * 19.9992f;

  float S = 0.f, ehk = eh[0];
#pragma unroll
  for (int k = 1; k < 8; ++k){
    bool sel = (idx >= k);
    S   += sel ? eh[k - 1] : 0.f;
    ehk  = sel ? eh[k]     : ehk;
  }
  float yk = fmaf(S, rh, fmaf((float)idx, 1e-4f, -10.f));
  float bh = fmaf(ehk, rh, 1e-4f);

  // ---- phase 3: derivatives (4 x b64 + 1 x b32; select 2 of 9) ----
  float dd[9];
#pragma unroll
  for (int k2 = 0; k2 < 4; ++k2){
    f32x2 v = *(const f32x2*)(pb + 64 + k2 * 8);
    dd[2*k2]   = v.x;
    dd[2*k2+1] = v.y;
  }
  dd[8] = *(const float*)(pb + 96);
  float uA = dd[0], uB = dd[1];
#pragma unroll
  for (int j = 1; j < 8; ++j){
    bool sel = (idx >= j);
    uA = sel ? dd[j]     : uA;
    uB = sel ? dd[j + 1] : uB;
  }
  float vA = uA + 0.54116666f;
  float dk  = fmaxf(vA, 0.f) + flog(1.f + fexp(-fabsf(vA))) + 1e-4f;
  float vB = uB + 0.54116666f;
  float dk1 = fmaxf(vB, 0.f) + flog(1.f + fexp(-fabsf(vB))) + 1e-4f;

  float rbw = frcp(bw);
  float s   = bh * rbw;
  float zf  = fminf(fmaxf((xv - xk) * rbw, 0.f), 1.f);
  float z1  = 1.f - zf;
  float zz  = zf * zf, z01 = zf * z1;
  float den = s + (dk1 + dk - 2.f * s) * z01;
  float rden = frcp(den);
  float yv  = yk + bh * (s * zz + dk * z01) * rden;
  float num = dk1 * zz + 2.f * s * z01 + dk * z1 * z1;
  float ldv = flog(s * s * num * rden * rden);

  bool outside = (xv <= -10.f) || (xv >= 10.f);
  y_out  = outside ? xv : yv;
  ld_out = outside ? 0.f : ldv;
}

// ---------------- prep kernel: pack fp16 B-fragments into ws ----------------
extern "C" __global__ void __launch_bounds__(256)
prep_kernel(const float* __restrict__ W1, const float* __restrict__ W2,
            const float* __restrict__ Wo, const float* __restrict__ bout,
            const float* __restrict__ scale, char* __restrict__ ws)
{
  int tid = blockIdx.x * 256 + threadIdx.x;
  if (tid < 1024){                       // W1 frags: [L][nt2]
    int fi = tid >> 6, lane = tid & 63;
    int l = fi >> 1, nt = fi & 1;
    int n = nt * 32 + (lane & 31), khi = lane >> 5;
    half8 h;
#pragma unroll
    for (int j = 0; j < 8; ++j){ int k = khi * 8 + j; h[j] = (f16)W1[l * 1024 + k * 64 + n]; }
    *(half8*)(ws + W1F_OFF + fi * 1024 + lane * 16) = h;
  } else if (tid < 5120){                // W2 frags: [L][kt4][nt2]
    int idx = tid - 1024;
    int fi = idx >> 6, lane = idx & 63;
    int l = fi >> 3, kt = (fi >> 1) & 3, nt = fi & 1;
    int n = nt * 32 + (lane & 31), khi = lane >> 5;
    half8 h;
#pragma unroll
    for (int j = 0; j < 8; ++j){ int k = kt * 16 + khi * 8 + j; h[j] = (f16)W2[l * 4096 + k * 64 + n]; }
    *(half8*)(ws + W2F_OFF + fi * 1024 + lane * 16) = h;
  } else if (tid < 21504){               // Wout used-col frags: [L][u8][kt4]
    int idx = tid - 5120;
    int fi = idx >> 6, lane = idx & 63;
    int l = fi >> 5, u = (fi >> 2) & 7, kt = fi & 3;
    int f = (l & 1) + 2 * u;
    int c = lane & 31, khi = lane >> 5;
    half8 h;
#pragma unroll
    for (int j = 0; j < 8; ++j){
      int k = kt * 16 + khi * 8 + j;
      float v = (c < 25) ? Wo[l * 25600 + k * 400 + f * 25 + c] : 0.f;
      h[j] = (f16)v;
    }
    *(half8*)(ws + WOF_OFF + fi * 1024 + lane * 16) = h;
  } else if (tid < 23552){               // bout used cols: [L][u8][32] fp32
    int idx = tid - 21504;
    int l = idx >> 8, u = (idx >> 5) & 7, c = idx & 31;
    int f = (l & 1) + 2 * u;
    float v = (c < 25) ? bout[l * 400 + f * 25 + c] : 0.f;
    ((float*)(ws + BOF_OFF))[idx] = v;
  } else if (tid == 23552){              // sum of log|scale| over all layers
    float acc = 0.f;
    for (int i = 0; i < 128; ++i) acc += logf(fabsf(scale[i]));
    *(float*)(ws + SUMLOG_OFF) = acc;
  }
}

// ---------------- one coupling layer ----------------
// Wave owns 32 samples; lane pair (ln31, khi=0/1) shares sample ln31.
// khi=0 splines features PAR+2it (it=0..3), khi=1 splines PAR+2it+8 —
// same instruction stream, no divergence. z exchanged via shfl_xor(32).
template<int PAR>
DEV void layer_mfma(int l,
                    const float* __restrict__ W0, const float* __restrict__ b0,
                    const float* __restrict__ b1v, const float* __restrict__ b2v,
                    const float* __restrict__ scv, const float* __restrict__ shv,
                    const char* __restrict__ ws, char* wlds /*per-wave chunk*/,
                    float (&z)[16], float &logdet,
                    int lane, int ln31, int khi)
{
  const float* w0  = W0 + l * 256;
  const float* bb0 = b0 + l * 16;
  const int rowbase = khi * 4;     // C/D layout: row = (i&3)+8*(i>>2)+4*khi

  const half8* W1F = (const half8*)(ws + W1F_OFF);
  const half8* W2F = (const half8*)(ws + W2F_OFF);
  const half8* WOF = (const half8*)(ws + WOF_OFF);
  const float* BOF = (const float*)(ws + BOF_OFF);

  // ---- hoisted W1 fragment + bias loads (latency hidden behind h0) ----
  half8 w1f[2];
#pragma unroll
  for (int nt = 0; nt < 2; ++nt) w1f[nt] = W1F[(l * 2 + nt) * 64 + lane];
  float bias1[2], bias2[2];
#pragma unroll
  for (int nt = 0; nt < 2; ++nt){
    bias1[nt] = b1v[l * 64 + nt * 32 + ln31];
    bias2[nt] = b2v[l * 64 + nt * 32 + ln31];
  }

  // ---- h0 = tanh(mz @ W0 + b0): scalar weights; keep own khi-half as
  //      the W1 A-fragment. No LDS round-trip. ----
  float h0[16];
#pragma unroll
  for (int j = 0; j < 16; ++j) h0[j] = bb0[j];
#pragma unroll
  for (int u = 0; u < 8; ++u){
    const int f = (1 - PAR) + 2 * u;
    const float v = z[f];
#pragma unroll
    for (int j = 0; j < 16; ++j) h0[j] = fmaf(v, w0[f * 16 + j], h0[j]);
  }
  half8 a0;
#pragma unroll
  for (int j = 0; j < 8; ++j){
    float hv = khi ? h0[j + 8] : h0[j];
    a0[j] = (f16)ftanh(hv);
  }

  // ---- W1: h1 = tanh(h0 @ W1 + b1), 1 m-tile ----
  f32x16 d1[2];
#pragma unroll
  for (int nt = 0; nt < 2; ++nt)
#pragma unroll
    for (int i = 0; i < 16; ++i) d1[nt][i] = bias1[nt];
#pragma unroll
  for (int nt = 0; nt < 2; ++nt)
    d1[nt] = __builtin_amdgcn_mfma_f32_32x32x16_f16(a0, w1f[nt], d1[nt], 0, 0, 0);

  // load W2 frags now; the d1 epilogue below covers the latency
  half8 w2f[8];
#pragma unroll
  for (int kt = 0; kt < 4; ++kt)
#pragma unroll
    for (int nt = 0; nt < 2; ++nt)
      w2f[kt * 2 + nt] = W2F[((l * 4 + kt) * 2 + nt) * 64 + lane];

#pragma unroll
  for (int nt = 0; nt < 2; ++nt)
#pragma unroll
    for (int i = 0; i < 16; ++i){
      int row = (i & 3) + 8 * (i >> 2) + rowbase;
      *(f16*)(wlds + row * H_STRIDE + (nt * 32 + ln31) * 2) = (f16)ftanh(d1[nt][i]);
    }

  // ---- W2: h2 = h1 @ W2 + b2 ----
  half8 a1[4];
#pragma unroll
  for (int kt = 0; kt < 4; ++kt)
    a1[kt] = *(const half8*)(wlds + ln31 * H_STRIDE + kt * 32 + khi * 16);
  f32x16 d2[2];
#pragma unroll
  for (int nt = 0; nt < 2; ++nt)
#pragma unroll
    for (int i = 0; i < 16; ++i) d2[nt][i] = bias2[nt];
#pragma unroll
  for (int kt = 0; kt < 4; ++kt)
#pragma unroll
    for (int nt = 0; nt < 2; ++nt)
      d2[nt] = __builtin_amdgcn_mfma_f32_32x32x16_f16(a1[kt], w2f[kt * 2 + nt], d2[nt], 0, 0, 0);

  // prefetch production 0's A-side Wout frags during the d2 epilogue
  half8 bfA[4];
#pragma unroll
  for (int kt = 0; kt < 4; ++kt) bfA[kt] = WOF[((l * 8 + 0) * 4 + kt) * 64 + lane];
  float biasA = BOF[(l * 8 + 0) * 32 + ln31];

#pragma unroll
  for (int nt = 0; nt < 2; ++nt)
#pragma unroll
    for (int i = 0; i < 16; ++i){
      int row = (i & 3) + 8 * (i >> 2) + rowbase;
      *(f16*)(wlds + row * H_STRIDE + (nt * 32 + ln31) * 2) = (f16)d2[nt][i];
    }

  // ---- h2 A-fragments (live across all 4 production iterations) ----
  half8 a2[4];
#pragma unroll
  for (int kt = 0; kt < 4; ++kt)
    a2[kt] = *(const half8*)(wlds + ln31 * H_STRIDE + kt * 32 + khi * 16);

  // ---- paired productions + splines (sequential dp to cap registers) ----
#pragma unroll 1
  for (int it = 0; it < 4; ++it){
    // B-side frags: issue loads, then cover latency with dpA's MFMA+store
    half8 bfB[4];
#pragma unroll
    for (int kt = 0; kt < 4; ++kt) bfB[kt] = WOF[((l * 8 + it + 4) * 4 + kt) * 64 + lane];
    float biasB = BOF[(l * 8 + it + 4) * 32 + ln31];

    {
      f32x16 dp;
#pragma unroll
      for (int i = 0; i < 16; ++i) dp[i] = biasA;
#pragma unroll
      for (int kt = 0; kt < 4; ++kt)
        dp = __builtin_amdgcn_mfma_f32_32x32x16_f16(a2[kt], bfA[kt], dp, 0, 0, 0);
      if (ln31 < 25){
#pragma unroll
        for (int i = 0; i < 16; ++i){
          int row = (i & 3) + 8 * (i >> 2) + rowbase;
          *(float*)(wlds + row * P_STRIDE + ln31 * 4) = dp[i];
        }
      }
    }
    {
      f32x16 dp;
#pragma unroll
      for (int i = 0; i < 16; ++i) dp[i] = biasB;
#pragma unroll
      for (int kt = 0; kt < 4; ++kt)
        dp = __builtin_amdgcn_mfma_f32_32x32x16_f16(a2[kt], bfB[kt], dp, 0, 0, 0);
      if (ln31 < 25){
#pragma unroll
        for (int i = 0; i < 16; ++i){
          int row = (i & 3) + 8 * (i >> 2) + rowbase;
          *(float*)(wlds + P_SLOT + row * P_STRIDE + ln31 * 4) = dp[i];
        }
      }
    }

    // prefetch next iteration's A-side frags; spline below hides the latency
    if (it < 3){
#pragma unroll
      for (int kt = 0; kt < 4; ++kt) bfA[kt] = WOF[((l * 8 + it + 1) * 4 + kt) * 64 + lane];
      biasA = BOF[(l * 8 + it + 1) * 32 + ln31];
    }

    // own-sample spline, params streamed from own khi-slot
    // (in-order per-wave DS + compiler aliasing on lds => reads stay after stores)
    const char* pb = wlds + khi * P_SLOT + ln31 * P_STRIDE;
    float xlo = z[PAR + 2 * it], xhi = z[PAR + 2 * it + 8];
    float xin = khi ? xhi : xlo;
    float y, ld;
    rq_spline_lds(pb, xin, y, ld);
    logdet += ld;
    z[PAR + 2 * it]     = khi ? xlo : y;
    z[PAR + 2 * it + 8] = khi ? y : xhi;
  }

  // ---- exchange transformed features between the khi-halves ----
#pragma unroll
  for (int it = 0; it < 4; ++it){
    float mine  = khi ? z[PAR + 2 * it + 8] : z[PAR + 2 * it];
    float other = __shfl_xor(mine, 32, 64);
    z[PAR + 2 * it]     = khi ? other : z[PAR + 2 * it];
    z[PAR + 2 * it + 8] = khi ? z[PAR + 2 * it + 8] : other;
  }

  // ---- affine (log|scale| sum precomputed in prep) ----
  const float* scp = scv + l * 16;
  const float* shp = shv + l * 16;
#pragma unroll
  for (int j = 0; j < 16; ++j)
    z[j] = fmaf(z[j], scp[j], shp[j]);
}

extern "C" __global__ void __launch_bounds__(256, 4)
flow_kernel(const float* __restrict__ x,
            const float* __restrict__ W0, const float* __restrict__ b0,
            const float* __restrict__ b1v, const float* __restrict__ b2v,
            const float* __restrict__ scv, const float* __restrict__ shv,
            const char* __restrict__ ws, float* __restrict__ out, int B)
{
  extern __shared__ char lds[];
  const int t    = threadIdx.x;
  const int lane = t & 63;
  const int wv   = t >> 6;
  const int ln31 = lane & 31;
  const int khi  = lane >> 5;
  char* wlds = lds + wv * WCHUNK;          // per-wave private chunk

  const int sid = wv * 32 + ln31;          // sample within block (0..127)
  const int g   = blockIdx.x * 128 + sid;  // global sample

  float z[16];
  const float4* xv = reinterpret_cast<const float4*>(x + (size_t)g * 16);
  float4 a0 = xv[0], a1 = xv[1], a2 = xv[2], a3 = xv[3];
  z[0]=a0.x; z[1]=a0.y; z[2]=a0.z; z[3]=a0.w;
  z[4]=a1.x; z[5]=a1.y; z[6]=a1.z; z[7]=a1.w;
  z[8]=a2.x; z[9]=a2.y; z[10]=a2.z; z[11]=a2.w;
  z[12]=a3.x; z[13]=a3.y; z[14]=a3.z; z[15]=a3.w;

  float logdet = 0.f;
  for (int l = 7; l >= 0; --l){
    if (l & 1) layer_mfma<1>(l, W0, b0, b1v, b2v, scv, shv, ws, wlds, z, logdet, lane, ln31, khi);
    else       layer_mfma<0>(l, W0, b0, b1v, b2v, scv, shv, ws, wlds, z, logdet, lane, ln31, khi);
  }

  // combine the pair's logdet halves
  float ldtot = logdet + __shfl_xor(logdet, 32, 64);

  float sumlog = *(const float*)(ws + SUMLOG_OFF);
  float ss = 0.f;
#pragma unroll
  for (int j = 0; j < 16; ++j) ss = fmaf(z[j], z[j], ss);
  if (khi == 0)
    out[g] = -0.5f * ss - 14.7030165f + ldtot + sumlog;
}

extern "C" void kernel_launch(void* const* d_in, const int* in_sizes, int n_in,
                              void* d_out, int out_size, void* d_ws, size_t ws_size,
                              hipStream_t stream)
{
  const float* x    = (const float*)d_in[0];
  const float* W0   = (const float*)d_in[1];
  const float* b0   = (const float*)d_in[2];
  const float* W1   = (const float*)d_in[3];
  const float* b1   = (const float*)d_in[4];
  const float* W2   = (const float*)d_in[5];
  const float* b2   = (const float*)d_in[6];
  const float* Wout = (const float*)d_in[7];
  const float* bout = (const float*)d_in[8];
  const float* scale= (const float*)d_in[9];
  const float* shift= (const float*)d_in[10];

  int B = in_sizes[0] / 16;

  hipLaunchKernelGGL(prep_kernel, dim3(93), dim3(256), 0, stream,
                     W1, W2, Wout, bout, scale, (char*)d_ws);

  hipLaunchKernelGGL(flow_kernel, dim3(B / 128), dim3(256), LDS_BYTES, stream,
                     x, W0, b0, b1, b2, scale, shift,
                     (const char*)d_ws, (float*)d_out, B);
}